// Round 8
// baseline (490.616 us; speedup 1.0000x reference)
//
#include <hip/hip_runtime.h>

#define NNODES 2000
#define BATCH  64
#define DIM    256
#define BLOCK  128
#define GRID   1024
#define NITEMS (2 * NNODES)
#define TBLD   264   // transpose-buffer row stride in shorts (pad 256->264 spreads banks)

typedef __attribute__((ext_vector_type(8))) short  v8s;
typedef __attribute__((ext_vector_type(8))) __bf16 v8bf;
typedef __attribute__((ext_vector_type(4))) float  v4f;
typedef __attribute__((ext_vector_type(4))) int    v4i;

__device__ __forceinline__ short f2bf(float f) {
  unsigned u = __builtin_bit_cast(unsigned, f);
  u += 0x7FFFu + ((u >> 16) & 1u);            // RNE
  return (short)(u >> 16);
}
__device__ __forceinline__ float bf2f(short s) {
  unsigned u = ((unsigned)(unsigned short)s) << 16;
  return __builtin_bit_cast(float, u);
}
__device__ __forceinline__ v4f mfma16(v8s a, v8s b, v4f c) {
  return __builtin_amdgcn_mfma_f32_16x16x32_bf16(
      __builtin_bit_cast(v8bf, a), __builtin_bit_cast(v8bf, b), c, 0, 0, 0);
}
__device__ __forceinline__ float sigmoidf(float x) {
  return __builtin_amdgcn_rcpf(1.0f + __builtin_amdgcn_exp2f(-1.4426950408889634f * x));
}

// prep1: weights transpose/fold; queue=-1; ccount=nc per (node,half); parent[]; head/tail=0.
__global__ void prep1_kernel(const float* __restrict__ W_in, const float* __restrict__ W_inner,
                             short* __restrict__ Wt_in, short* __restrict__ Wt_inner,
                             const int* __restrict__ structure, int* __restrict__ parent,
                             int* __restrict__ ccount, int* __restrict__ queue,
                             int* __restrict__ qctl) {
  int idx = blockIdx.x * blockDim.x + threadIdx.x;
  int stride = gridDim.x * blockDim.x;
  for (int i = idx; i < 256 * 256; i += stride) {
    int j = i >> 8, k = i & 255;
    Wt_in[j * 256 + k] = f2bf(W_in[k * 256 + j]);
  }
  for (int i = idx; i < 256 * 512; i += stride) {
    int j = i >> 9, k = i & 511;
    float v = W_inner[(k + 256) * 256 + j];
    if (k < 256) v += W_inner[k * 256 + j];
    Wt_inner[j * 512 + k] = f2bf(v);
  }
  for (int i = idx; i < NITEMS; i += stride)
    __hip_atomic_store(&queue[i], -1, __ATOMIC_RELAXED, __HIP_MEMORY_SCOPE_AGENT);
  for (int i = idx; i < NNODES; i += stride) {
    const int s = structure[2 * i], e = structure[2 * i + 1];
    const int nc = (s < 0) ? 0 : (e - s);
    __hip_atomic_store(&ccount[2 * i],     nc, __ATOMIC_RELAXED, __HIP_MEMORY_SCOPE_AGENT);
    __hip_atomic_store(&ccount[2 * i + 1], nc, __ATOMIC_RELAXED, __HIP_MEMORY_SCOPE_AGENT);
    if (s >= 0)
      for (int c = s; c < e; ++c) parent[c] = i;   // each child has exactly one parent
  }
  if (idx == 0) {
    __hip_atomic_store(&qctl[0], 0, __ATOMIC_RELAXED, __HIP_MEMORY_SCOPE_AGENT);  // head
    __hip_atomic_store(&qctl[1], 0, __ATOMIC_RELAXED, __HIP_MEMORY_SCOPE_AGENT);  // tail
  }
}

// prep2 (after prep1): push all leaf items (both halves). Runs after queue init.
__global__ void prep2_kernel(const int* __restrict__ structure,
                             int* __restrict__ queue, int* __restrict__ qctl) {
  int idx = blockIdx.x * blockDim.x + threadIdx.x;
  int stride = gridDim.x * blockDim.x;
  for (int i = idx; i < NNODES; i += stride) {
    if (structure[2 * i] < 0) {
      #pragma unroll
      for (int h = 0; h < 2; ++h) {
        const int slot = __hip_atomic_fetch_add(&qctl[1], 1, __ATOMIC_RELAXED, __HIP_MEMORY_SCOPE_AGENT);
        __hip_atomic_store(&queue[slot], 2 * i + h, __ATOMIC_RELAXED, __HIP_MEMORY_SCOPE_AGENT);
      }
    }
  }
}

// Ready-queue dataflow tree evaluation, zero cache-flush fences (R4-verified
// sc0sc1/IF coherence for all cross-block data).
// R4-R7 showed wall ~285us pinned regardless of item size / transaction count /
// W traffic / block count -> static descending-stride assignment left blocks
// idling on THEIR next item's deps while ready items existed (per-block round
// structure x intra-round dependency chains). This version schedules by
// readiness: last-finishing child pushes the parent item; blocks pop tickets.
// Every popped item is immediately runnable -> deadlock-free even without
// co-residency (plain launch, no cooperative capacity hazard).
__launch_bounds__(BLOCK, 2)
__global__ void tree_kernel(const int* __restrict__ structure, const float* __restrict__ features,
                            const float* __restrict__ b_in, const float* __restrict__ b_inner,
                            const short* __restrict__ Wt_in, const short* __restrict__ Wt_inner,
                            const int* __restrict__ parent,
                            short* __restrict__ state, int* __restrict__ ccount,
                            int* __restrict__ queue, int* __restrict__ qctl,
                            float* __restrict__ out) {
  // 32 batch rows x 512 k (bf16), XOR-swizzled chunks: phys chunk = (k>>3) ^ (row&7).
  // Reused after the GEMM as a [32][TBLD] transpose tile (32*264=8448 < 16384 shorts).
  __shared__ short Xs[32 * 512];   // 32 KiB
  __shared__ int curitem;

  const int tid  = threadIdx.x;
  const int wave = tid >> 6;       // 0..1
  const int lane = tid & 63;
  const int ln15 = lane & 15;
  const int quad = lane >> 4;
  const int rl3  = ln15 & 7;

  const int rowb = tid >> 5;       // 0..3: base row for pooling/stores
  const int ch   = tid & 31;       // 16B chunk within a 512B state row

  // j = wave*128 + nt*16 + ln15 is item-invariant: hoist bias loads
  float bia_in[8], bia_nn[8];
  #pragma unroll
  for (int nt = 0; nt < 8; ++nt) {
    const int j = wave * 128 + nt * 16 + ln15;
    bia_in[nt] = b_in[j];
    bia_nn[nt] = b_inner[j];
  }

  while (true) {
    __syncthreads();   // WAR on Xs + curitem from previous item
    if (tid == 0) {
      int it = -1;
      const int t = __hip_atomic_fetch_add(&qctl[0], 1, __ATOMIC_RELAXED, __HIP_MEMORY_SCOPE_AGENT);
      if (t < NITEMS) {
        int g = 0;
        while ((it = __hip_atomic_load(&queue[t], __ATOMIC_RELAXED, __HIP_MEMORY_SCOPE_AGENT)) < 0 &&
               g < (1 << 24)) {
          __builtin_amdgcn_s_sleep(1); ++g;
        }
      }
      curitem = it;
    }
    __syncthreads();
    const int item = curitem;
    if (item < 0) break;

    const int node = item >> 1;
    const int half = item & 1;
    const int s = structure[2 * node];
    const int e = structure[2 * node + 1];
    const bool leaf = (s < 0);
    const int nc = e - s;               // 1..4 when inner
    const int K = leaf ? 256 : 512;
    const short* __restrict__ W = leaf ? Wt_in : Wt_inner;

    // ---- build Xs (bf16) for the half's 32 rows: two 16-row passes (bounds VGPRs) ----
    for (int pass = 0; pass < 2; ++pass) {
      float4 pf[4][2];
      #pragma unroll
      for (int g = 0; g < 4; ++g) {
        const int b = half * 32 + pass * 16 + rowb + 4 * g;
        const float* __restrict__ fp = features + ((size_t)b * NNODES + node) * DIM + ch * 8;
        pf[g][0] = ((const float4*)fp)[0];
        pf[g][1] = ((const float4*)fp)[1];
      }
      if (leaf) {
        #pragma unroll
        for (int g = 0; g < 4; ++g) {
          const int row = pass * 16 + rowb + 4 * g;
          const int sw  = row & 7;
          const float4 f0 = pf[g][0], f1 = pf[g][1];
          v8s o;
          o[0] = f2bf(f0.x); o[1] = f2bf(f0.y); o[2] = f2bf(f0.z); o[3] = f2bf(f0.w);
          o[4] = f2bf(f1.x); o[5] = f2bf(f1.y); o[6] = f2bf(f1.z); o[7] = f2bf(f1.w);
          *(v8s*)&Xs[(row << 9) + ((ch ^ sw) << 3)] = o;
        }
      } else {
        // coalesced child loads: sc0sc1 (bypass stale L1/L2, coherent at IF);
        // one wave64 instruction reads 2 contiguous 512B rows. All issued, one waitcnt.
        v4i cb[4][4];   // [ci][g]
        #pragma unroll
        for (int ci = 0; ci < 4; ++ci) {
          if (ci < nc) {   // block-uniform branch
            #pragma unroll
            for (int g = 0; g < 4; ++g) {
              const short* cp = state +
                  ((size_t)(s + ci) * BATCH + half * 32 + pass * 16 + rowb + 4 * g) * DIM + ch * 8;
              asm volatile("global_load_dwordx4 %0, %1, off sc0 sc1"
                           : "=v"(cb[ci][g]) : "v"(cp));
            }
          }
        }
        asm volatile("s_waitcnt vmcnt(0)" ::: "memory");
        __builtin_amdgcn_sched_barrier(0);   // rule #18: pin VALU uses after the wait

        const float inv = 1.0f / (float)(nc + 1);
        #pragma unroll
        for (int g = 0; g < 4; ++g) {
          const int row = pass * 16 + rowb + 4 * g;
          const int sw  = row & 7;
          const float4 f0 = pf[g][0], f1 = pf[g][1];
          float sm[8] = {f0.x, f0.y, f0.z, f0.w, f1.x, f1.y, f1.z, f1.w};
          float mn[8];
          #pragma unroll
          for (int qq = 0; qq < 8; ++qq) mn[qq] = sm[qq];
          #pragma unroll
          for (int ci = 0; ci < 4; ++ci) {
            if (ci < nc) {
              const v8s cv = __builtin_bit_cast(v8s, cb[ci][g]);
              #pragma unroll
              for (int qq = 0; qq < 8; ++qq) {
                const float v = bf2f(cv[qq]);
                sm[qq] += v; mn[qq] = fminf(mn[qq], v);
              }
            }
          }
          v8s om, on;
          #pragma unroll
          for (int qq = 0; qq < 8; ++qq) { om[qq] = f2bf(sm[qq] * inv); on[qq] = f2bf(mn[qq]); }
          *(v8s*)&Xs[(row << 9) + ((ch ^ sw) << 3)]        = om;  // c_mean: k in [0,256)
          *(v8s*)&Xs[(row << 9) + (((ch + 32) ^ sw) << 3)] = on;  // c_min:  k in [256,512)
        }
      }
    }
    __syncthreads();   // Xs ready

    // ---- GEMM: [32 x K] @ Wt^T -> [32 x 256]; 2 waves x 128 cols; W from L2 ----
    v4f acc[2][8];
    #pragma unroll
    for (int mt = 0; mt < 2; ++mt)
      #pragma unroll
      for (int nt = 0; nt < 8; ++nt) acc[mt][nt] = v4f{0.f, 0.f, 0.f, 0.f};

    const short* __restrict__ Wp = W + (size_t)(wave * 128 + ln15) * K + quad * 8;
    const int nkc = K >> 5;
    v8s bcur[8];
    #pragma unroll
    for (int nt = 0; nt < 8; ++nt) bcur[nt] = *(const v8s*)(Wp + (size_t)nt * 16 * K);
    for (int kc = 0; kc < nkc; ++kc) {
      const int kn = (kc + 1 < nkc) ? kc + 1 : kc;   // last iter: harmless re-load
      v8s bnxt[8];
      #pragma unroll
      for (int nt = 0; nt < 8; ++nt) bnxt[nt] = *(const v8s*)(Wp + (size_t)nt * 16 * K + kn * 32);
      v8s af[2];
      #pragma unroll
      for (int mt = 0; mt < 2; ++mt) {
        const int r = mt * 16 + ln15;               // r&7 == rl3
        af[mt] = *(const v8s*)&Xs[(r << 9) + (((kc * 4 + quad) ^ rl3) << 3)];
      }
      #pragma unroll
      for (int mt = 0; mt < 2; ++mt)
        #pragma unroll
        for (int nt = 0; nt < 8; ++nt)
          acc[mt][nt] = mfma16(af[mt], bcur[nt], acc[mt][nt]);
      #pragma unroll
      for (int nt = 0; nt < 8; ++nt) bcur[nt] = bnxt[nt];
    }
    __syncthreads();   // all Xs reads done before transpose-tile overwrite

    // ---- epilogue: bias + sigmoid -> LDS transpose tile [32][TBLD] ----
    #pragma unroll
    for (int nt = 0; nt < 8; ++nt) {
      const int j = wave * 128 + nt * 16 + ln15;
      const float bs = leaf ? bia_in[nt] : bia_nn[nt];
      #pragma unroll
      for (int mt = 0; mt < 2; ++mt) {
        #pragma unroll
        for (int r = 0; r < 4; ++r) {
          const int bb = mt * 16 + quad * 4 + r;   // 0..31 (row within half-slab)
          const float v = sigmoidf(acc[mt][nt][r] + bs);
          Xs[bb * TBLD + j] = f2bf(v);
          if (node == 0) out[(half * 32 + bb) * DIM + j] = v;   // exact fp32, root only
        }
      }
    }
    __syncthreads();   // transpose tile ready

    // ---- coalesced state store: 8 x dwordx4 sc0sc1 per thread (16KB contiguous) ----
    #pragma unroll
    for (int g = 0; g < 8; ++g) {
      const int row = rowb + 4 * g;                // 0..31
      const v4i val = *(const v4i*)&Xs[row * TBLD + ch * 8];
      short* sp = state + ((size_t)node * BATCH + half * 32 + row) * DIM + ch * 8;
      asm volatile("global_store_dwordx4 %0, %1, off sc0 sc1" :: "v"(sp), "v"(val));
    }

    asm volatile("s_waitcnt vmcnt(0)" ::: "memory");  // this thread's stores are at IF
    __syncthreads();                                  // => ALL threads' stores are at IF
    if (tid == 0 && node > 0) {
      const int p = parent[node];
      const int old = __hip_atomic_fetch_add(&ccount[2 * p + half], -1,
                                             __ATOMIC_RELAXED, __HIP_MEMORY_SCOPE_AGENT);
      if (old == 1) {   // last child: parent (same half) is ready -> push
        const int slot = __hip_atomic_fetch_add(&qctl[1], 1,
                                                __ATOMIC_RELAXED, __HIP_MEMORY_SCOPE_AGENT);
        __hip_atomic_store(&queue[slot], 2 * p + half,
                           __ATOMIC_RELAXED, __HIP_MEMORY_SCOPE_AGENT);
      }
    }
  }
}

extern "C" void kernel_launch(void* const* d_in, const int* in_sizes, int n_in,
                              void* d_out, int out_size, void* d_ws, size_t ws_size,
                              hipStream_t stream) {
  const int*   structure = (const int*)d_in[0];
  const float* features  = (const float*)d_in[1];
  const float* W_in      = (const float*)d_in[2];
  const float* b_in      = (const float*)d_in[3];
  const float* W_inner   = (const float*)d_in[4];
  const float* b_inner   = (const float*)d_in[5];
  float* out = (float*)d_out;

  char* ws = (char*)d_ws;
  short* state = (short*)ws;                                   // 2000*64*256*2 = 65,536,000 B
  size_t off = (size_t)NNODES * BATCH * DIM * 2;
  short* Wt_in = (short*)(ws + off);    off += 256 * 256 * 2;  // 131,072 B
  short* Wt_inner = (short*)(ws + off); off += 512 * 256 * 2;  // 262,144 B
  int* parent = (int*)(ws + off);       off += NNODES * 4;     // 8,000 B
  int* ccount = (int*)(ws + off);       off += NITEMS * 4;     // 16,000 B
  int* queue  = (int*)(ws + off);       off += NITEMS * 4;     // 16,000 B
  int* qctl   = (int*)(ws + off);                               // 8 B

  prep1_kernel<<<dim3(256), dim3(256), 0, stream>>>(W_in, W_inner, Wt_in, Wt_inner,
                                                    structure, parent, ccount, queue, qctl);
  prep2_kernel<<<dim3(64), dim3(256), 0, stream>>>(structure, queue, qctl);

  tree_kernel<<<dim3(GRID), dim3(BLOCK), 0, stream>>>(
      structure, features, b_in, b_inner, Wt_in, Wt_inner, parent,
      state, ccount, queue, qctl, out);
}